// Round 3
// baseline (304.553 us; speedup 1.0000x reference)
//
#include <hip/hip_runtime.h>
#include <stdint.h>
#include <math.h>

typedef float fx4 __attribute__((ext_vector_type(4)));
typedef short sx8 __attribute__((ext_vector_type(8)));
typedef __bf16 bfx8 __attribute__((ext_vector_type(8)));
typedef unsigned short ux4 __attribute__((ext_vector_type(4)));

#define NB 4096
#define ND 1024
#define CEPS 1e-6f
#define CTHR 0.5f
#define NT 16            // K-tiles of 64: 1024/64

// ---------- helpers ----------

__device__ __forceinline__ unsigned short f2bf(float f) {
  uint32_t u = __builtin_bit_cast(uint32_t, f);
  u = u + 0x7FFFu + ((u >> 16) & 1u);   // RNE
  return (unsigned short)(u >> 16);
}

__device__ __forceinline__ void gload16(const void* g, void* l) {
  __builtin_amdgcn_global_load_lds(
      (const __attribute__((address_space(1))) uint32_t*)(uintptr_t)g,
      (__attribute__((address_space(3))) uint32_t*)(uint32_t)(uintptr_t)l,
      16, 0, 0);
}

__device__ __forceinline__ bfx8 ldfrag(const unsigned short* p) {
  sx8 r = *(const sx8*)p;
  return __builtin_bit_cast(bfx8, r);
}

#define MFMA(A, B, C) __builtin_amdgcn_mfma_f32_16x16x32_bf16((A), (B), (C), 0, 0, 0)

// ---------- kernel 1: f32 -> bf16 convert + row norms (f32) ----------

__global__ __launch_bounds__(256) void cmc_convert(
    const float* __restrict__ in, unsigned short* __restrict__ xb,
    float* __restrict__ lnorm) {
  const int row = blockIdx.x;           // 0 .. 3*4096-1
  const int tid = threadIdx.x;
  const fx4 v = *(const fx4*)(in + (size_t)row * ND + tid * 4);
  ux4 o;
  o[0] = f2bf(v[0]); o[1] = f2bf(v[1]); o[2] = f2bf(v[2]); o[3] = f2bf(v[3]);
  *(ux4*)(xb + (size_t)row * ND + tid * 4) = o;
  float ss = v[0]*v[0] + v[1]*v[1] + v[2]*v[2] + v[3]*v[3];
  #pragma unroll
  for (int d = 1; d < 64; d <<= 1) ss += __shfl_xor(ss, d);
  __shared__ float sred[4];
  if ((tid & 63) == 0) sred[tid >> 6] = ss;
  __syncthreads();
  if (tid == 0) lnorm[row] = sqrtf(sred[0] + sred[1] + sred[2] + sred[3]);
}

// ---------- 256x256 gram, BK=64, 8 waves, double-buffered + counted vmcnt ----------
// LDS layout per buffer (2 buffers, 64 KiB each):
//   A-tile at +0      : 256 rows x 64 bf16, row stride 128 B, XOR-swizzled
//   B-tile at +32768  : same
// Swizzle: element (r,c) lives at byte r*128 + ((c*2) ^ ((r&7)<<4)).
// global_load_lds writes LINEARLY (wave base + lane*16); the source address is
// pre-swizzled per-lane so linear-dest == swizzled layout (rule #21).

__device__ __forceinline__ void stage_tile(char* smem, int t, int w,
    const unsigned short* const (&pA)[4], const unsigned short* const (&pB)[4]) {
  char* dA = smem + (t & 1) * 65536;
  char* dB = dA + 32768;
  const int k0 = t * 64;
  #pragma unroll
  for (int s = 0; s < 4; ++s) {
    gload16(pA[s] + k0, dA + s * 8192 + w * 1024);
    gload16(pB[s] + k0, dB + s * 8192 + w * 1024);
  }
}

template<int VM, bool DO_STAGE>
__device__ __forceinline__ void ktile(char* smem, int t, int w,
    const unsigned short* const (&pA)[4], const unsigned short* const (&pB)[4],
    int rdA0, int rdB0, fx4 (&acc)[8][4]) {
  char* bufA = smem + (t & 1) * 65536;
  char* bufB = bufA + 32768;
  // ---- P0: gate on our K-tile landed (counted, never 0 in steady state) ----
  if (VM == 8) asm volatile("s_waitcnt vmcnt(8)" ::: "memory");
  else         asm volatile("s_waitcnt vmcnt(0)" ::: "memory");
  __builtin_amdgcn_s_barrier();          // all waves' stage(t) landed
  __builtin_amdgcn_sched_barrier(0);     // nothing moves above the barrier
  bfx8 a[8], b[8];
  #pragma unroll
  for (int n = 0; n < 4; ++n) {
    const int ro = rdB0 + n * 2048;
    b[n*2]   = ldfrag((const unsigned short*)(bufB + ro));
    b[n*2+1] = ldfrag((const unsigned short*)(bufB + (ro ^ 64)));
  }
  #pragma unroll
  for (int m = 0; m < 4; ++m) {
    const int ro = rdA0 + m * 2048;
    a[m*2]   = ldfrag((const unsigned short*)(bufA + ro));
    a[m*2+1] = ldfrag((const unsigned short*)(bufA + (ro ^ 64)));
  }
  __builtin_amdgcn_s_setprio(1);
  #pragma unroll
  for (int m = 0; m < 4; ++m)
    #pragma unroll
    for (int n = 0; n < 4; ++n) {
      acc[m][n] = MFMA(a[m*2],   b[n*2],   acc[m][n]);
      acc[m][n] = MFMA(a[m*2+1], b[n*2+1], acc[m][n]);
    }
  __builtin_amdgcn_s_setprio(0);
  __builtin_amdgcn_s_barrier();          // phase split (role diversity for setprio)
  // ---- P1: read A[m4-7]; prove all reads of buf[t&1] done; then stage t+2 into it ----
  #pragma unroll
  for (int m = 0; m < 4; ++m) {
    const int ro = rdA0 + (m + 4) * 2048;
    a[m*2]   = ldfrag((const unsigned short*)(bufA + ro));
    a[m*2+1] = ldfrag((const unsigned short*)(bufA + (ro ^ 64)));
  }
  asm volatile("s_waitcnt lgkmcnt(0)" ::: "memory");  // my reads complete
  __builtin_amdgcn_sched_barrier(0);
  __builtin_amdgcn_s_barrier();          // ALL waves' reads of buf[t&1] complete
  __builtin_amdgcn_sched_barrier(0);     // stage must not hoist above barrier
  if (DO_STAGE) stage_tile(smem, t + 2, w, pA, pB);   // writes land post-read: race-free
  __builtin_amdgcn_s_setprio(1);
  #pragma unroll
  for (int m = 0; m < 4; ++m)
    #pragma unroll
    for (int n = 0; n < 4; ++n) {
      acc[m][n] = MFMA(a[m*2],   b[n*2],   acc[m][n]);
      acc[m][n] = MFMA(a[m*2+1], b[n*2+1], acc[m][n]);
    }
  __builtin_amdgcn_s_setprio(0);
  // next ktile's P0 (vmcnt + barrier) is the closing sync
}

__device__ __forceinline__ void gram256(
    const unsigned short* __restrict__ Xi, const unsigned short* __restrict__ Xj,
    int rb, int cb, char* smem, int tid, fx4 (&acc)[8][4]) {
  const int l = tid & 63, w = tid >> 6;
  const int wr = w >> 2, wc = w & 3;
  const int lrow = l >> 3, slot = l & 7;
  // pre-swizzled global source (element offset within row)
  const int srcoff = ((slot * 16) ^ (lrow << 4)) >> 1;
  const unsigned short* pA[4];
  const unsigned short* pB[4];
  #pragma unroll
  for (int s = 0; s < 4; ++s) {
    pA[s] = Xi + (size_t)(rb + s * 64 + w * 8 + lrow) * ND + srcoff;
    pB[s] = Xj + (size_t)(cb + s * 64 + w * 8 + lrow) * ND + srcoff;
  }
  // swizzled read offsets: frag(m,kh) lane l -> row base + (l&15), colbyte (l>>4)*16 (+kh*64)
  const int c0 = ((l >> 4) * 16) ^ ((l & 7) << 4);
  const int rdA0 = (wr * 128 + (l & 15)) * 128 + c0;
  const int rdB0 = (wc * 64 + (l & 15)) * 128 + c0;
  #pragma unroll
  for (int m = 0; m < 8; ++m)
    #pragma unroll
    for (int n = 0; n < 4; ++n) acc[m][n] = fx4{0.f, 0.f, 0.f, 0.f};

  stage_tile(smem, 0, w, pA, pB);        // 8 loads
  stage_tile(smem, 1, w, pA, pB);        // 8 loads  -> 16 outstanding
  for (int t = 0; t < NT - 2; ++t)
    ktile<8, true>(smem, t, w, pA, pB, rdA0, rdB0, acc);
  ktile<8, false>(smem, NT - 2, w, pA, pB, rdA0, rdB0, acc);
  ktile<0, false>(smem, NT - 1, w, pA, pB, rdA0, rdB0, acc);
  // all staging consumed; vmcnt drained at last tile; LDS free after this point
}

// ---------- kernel 2: per-modal self-gram -> bitmask (upper-tri + transpose) ----------

__global__ __launch_bounds__(512, 2) void cmc_selfmask(
    const unsigned short* __restrict__ xb, const float* __restrict__ lnorm,
    uint32_t* __restrict__ maskw) {
  __shared__ __align__(16) char smem[131072];
  const int md = blockIdx.z;
  const int bx = blockIdx.x, by = blockIdx.y;
  if (by > bx) return;                   // symmetric: upper triangle only
  const int rb = by * 256, cb = bx * 256;
  const int tid = threadIdx.x;
  const int l = tid & 63, w = tid >> 6;
  const int wr = w >> 2, wc = w & 3;
  const int g = l >> 4;

  const unsigned short* X = xb + (size_t)md * NB * ND;
  fx4 acc[8][4];
  gram256(X, X, rb, cb, smem, tid, acc);

  // epilogue: threshold -> 256x256 bit tile in LDS (reuse smem)
  uint32_t* tile = (uint32_t*)smem;      // [256][8] words = 8 KiB
  float* Lr = (float*)(smem + 8192);
  float* Lc = (float*)(smem + 9216);
  if (tid < 256) {
    Lr[tid] = lnorm[md * NB + rb + tid];
    Lc[tid] = lnorm[md * NB + cb + tid];
  }
  __syncthreads();

  #pragma unroll
  for (int m = 0; m < 8; ++m)
    #pragma unroll
    for (int r4 = 0; r4 < 4; ++r4) {
      const int rl = wr * 128 + m * 16 + g * 4 + r4;
      uint64_t bb[4];
      #pragma unroll
      for (int n = 0; n < 4; ++n) {
        const int cl = wc * 64 + n * 16 + (l & 15);
        const float cv = acc[m][n][r4] / fmaxf(Lr[rl] * Lc[cl], CEPS);
        bb[n] = __ballot(cv <= CTHR);
      }
      if ((l & 15) == 0) {
        const uint32_t w0 = (uint32_t)((bb[0] >> (16 * g)) & 0xFFFF) |
                            ((uint32_t)((bb[1] >> (16 * g)) & 0xFFFF) << 16);
        const uint32_t w1 = (uint32_t)((bb[2] >> (16 * g)) & 0xFFFF) |
                            ((uint32_t)((bb[3] >> (16 * g)) & 0xFFFF) << 16);
        tile[rl * 8 + wc * 2]     = w0;
        tile[rl * 8 + wc * 2 + 1] = w1;
      }
    }
  __syncthreads();

  // direct region: rows [rb,+256) x words [cb/32,+8) — exclusively owned
  for (int t = tid; t < 2048; t += 512) {
    const int row = t >> 3, wd = t & 7;
    maskw[((size_t)md * NB + rb + row) * 128 + (cb >> 5) + wd] = tile[t];
  }
  // transposed region: rows [cb,+256) x words [rb/32,+8)
  if (by != bx) {
    for (int t = tid; t < 2048; t += 512) {
      const int crow = t & 255;
      const int wp = t >> 8;
      uint32_t wv = 0;
      #pragma unroll
      for (int r = 0; r < 32; ++r) {
        const uint32_t bit = (tile[(wp * 32 + r) * 8 + (crow >> 5)] >> (crow & 31)) & 1u;
        wv |= bit << r;
      }
      maskw[((size_t)md * NB + cb + crow) * 128 + (rb >> 5) + wp] = wv;
    }
  }
}

// ---------- kernel 3: per-pair cross gram + masked exp row-partials ----------

__global__ __launch_bounds__(512, 2) void cmc_pair(
    const unsigned short* __restrict__ xb, const float* __restrict__ lnorm,
    const uint32_t* __restrict__ maskw,
    float* __restrict__ sumexp, float* __restrict__ cntrow,
    float* __restrict__ diagv) {
  __shared__ __align__(16) char smem[131072];
  const int p = blockIdx.z;              // pair: 0->(0,1) 1->(0,2) 2->(1,2)
  const int mi = (p == 2) ? 1 : 0;
  const int mj = (p == 0) ? 1 : 2;
  const int rb = blockIdx.y * 256;
  const int cb = blockIdx.x * 256;
  const int tid = threadIdx.x;
  const int l = tid & 63, w = tid >> 6;
  const int wr = w >> 2, wc = w & 3;
  const int g = l >> 4;

  const unsigned short* Xi = xb + (size_t)mi * NB * ND;
  const unsigned short* Xj = xb + (size_t)mj * NB * ND;

  fx4 acc[8][4];
  gram256(Xi, Xj, rb, cb, smem, tid, acc);

  // epilogue: stage masks + norms into LDS (reuse smem)
  uint32_t* Mt = (uint32_t*)smem;        // Mi [256][8] then Mj [256][8]
  float* Lri = (float*)(smem + 16384);
  float* Lcj = (float*)(smem + 17408);
  for (int t = tid; t < 2048; t += 512) {
    const int row = t >> 3, wd = t & 7;
    Mt[t]        = maskw[((size_t)mi * NB + rb + row) * 128 + (cb >> 5) + wd];
    Mt[2048 + t] = maskw[((size_t)mj * NB + rb + row) * 128 + (cb >> 5) + wd];
  }
  if (tid < 256) {
    Lri[tid] = lnorm[mi * NB + rb + tid];
    Lcj[tid] = lnorm[mj * NB + cb + tid];
  }
  __syncthreads();

  #pragma unroll
  for (int m = 0; m < 8; ++m)
    #pragma unroll
    for (int r4 = 0; r4 < 4; ++r4) {
      const int rl = wr * 128 + m * 16 + g * 4 + r4;
      const int rg = rb + rl;
      float se = 0.f, ct = 0.f;
      #pragma unroll
      for (int n = 0; n < 4; ++n) {
        const int cl = wc * 64 + n * 16 + (l & 15);
        const int cg = cb + cl;
        const uint32_t bi = (Mt[rl * 8 + (cl >> 5)] >> (cl & 31)) & 1u;
        const uint32_t bj = (Mt[2048 + rl * 8 + (cl >> 5)] >> (cl & 31)) & 1u;
        const bool msk = bi | bj | (rg == cg);
        const float logit = acc[m][n][r4] / fmaxf(Lri[rl] * Lcj[cl], CEPS) / 0.1f;
        if (rg == cg) diagv[p * NB + rg] = logit;
        if (msk) { se += __expf(logit); ct += 1.f; }
      }
      #pragma unroll
      for (int d0 = 1; d0 < 16; d0 <<= 1) {
        se += __shfl_xor(se, d0);
        ct += __shfl_xor(ct, d0);
      }
      if ((l & 15) == 0) {
        atomicAdd(&sumexp[p * NB + rg], se);
        atomicAdd(&cntrow[p * NB + rg], ct);
      }
    }
}

// ---------- kernel 4: finalize ----------

__global__ __launch_bounds__(256) void cmc_final(
    const float* __restrict__ sumexp, const float* __restrict__ cntrow,
    const float* __restrict__ diagv, float* __restrict__ out) {
  const int tid = threadIdx.x;
  __shared__ float sred[8];
  float lsum = 0.f;
  for (int p = 0; p < 3; ++p) {
    float t = 0.f, c = 0.f;
    for (int r = tid; r < NB; r += 256) {
      const float cnt = cntrow[p * NB + r];
      if (cnt > 1.0f) {
        t += logf(sumexp[p * NB + r]) - diagv[p * NB + r];
        c += 1.f;
      }
    }
    #pragma unroll
    for (int d = 1; d < 64; d <<= 1) { t += __shfl_xor(t, d); c += __shfl_xor(c, d); }
    if ((tid & 63) == 0) { sred[(tid >> 6) * 2] = t; sred[(tid >> 6) * 2 + 1] = c; }
    __syncthreads();
    if (tid == 0) {
      const float tt = sred[0] + sred[2] + sred[4] + sred[6];
      const float cc = sred[1] + sred[3] + sred[5] + sred[7];
      lsum += (cc > 0.f) ? tt / fmaxf(cc, 1.f) : 0.f;
    }
    __syncthreads();
  }
  if (tid == 0) out[0] = lsum / 3.0f;
}

// ---------- launch ----------

extern "C" void kernel_launch(void* const* d_in, const int* in_sizes, int n_in,
                              void* d_out, int out_size, void* d_ws, size_t ws_size,
                              hipStream_t stream) {
  const float* in = (const float*)d_in[0];
  float* out = (float*)d_out;
  char* ws = (char*)d_ws;

  const size_t XB_BYTES = (size_t)3 * NB * ND * sizeof(unsigned short); // 25,165,824
  unsigned short* xb = (unsigned short*)ws;
  float* lnorm  = (float*)(ws + XB_BYTES);
  float* sumexp = lnorm + 3 * NB;
  float* cntrow = sumexp + 3 * NB;
  float* diagv  = cntrow + 3 * NB;
  uint32_t* maskw = (uint32_t*)(diagv + 3 * NB);   // [3][4096][128] words = 6 MB

  // zero the atomically-accumulated per-row buffers (sumexp + cntrow contiguous)
  hipMemsetAsync(sumexp, 0, (size_t)2 * 3 * NB * sizeof(float), stream);

  cmc_convert<<<3 * NB, 256, 0, stream>>>(in, xb, lnorm);
  cmc_selfmask<<<dim3(NB / 256, NB / 256, 3), 512, 0, stream>>>(xb, lnorm, maskw);
  cmc_pair<<<dim3(NB / 256, NB / 256, 3), 512, 0, stream>>>(xb, lnorm, maskw, sumexp, cntrow, diagv);
  cmc_final<<<1, 256, 0, stream>>>(sumexp, cntrow, diagv, out);
}

// Round 4
// 298.875 us; speedup vs baseline: 1.0190x; 1.0190x over previous
//
#include <hip/hip_runtime.h>
#include <stdint.h>
#include <math.h>

typedef float fx4 __attribute__((ext_vector_type(4)));
typedef short sx8 __attribute__((ext_vector_type(8)));
typedef __bf16 bfx8 __attribute__((ext_vector_type(8)));
typedef unsigned short ux4 __attribute__((ext_vector_type(4)));

#define NB 4096
#define ND 1024
#define CEPS 1e-6f
#define CTHR 0.5f
#define NT 16            // K-tiles of 64: 1024/64

// ---------- helpers ----------

__device__ __forceinline__ unsigned short f2bf(float f) {
  uint32_t u = __builtin_bit_cast(uint32_t, f);
  u = u + 0x7FFFu + ((u >> 16) & 1u);   // RNE
  return (unsigned short)(u >> 16);
}

__device__ __forceinline__ void gload16(const void* g, void* l) {
  __builtin_amdgcn_global_load_lds(
      (const __attribute__((address_space(1))) uint32_t*)(uintptr_t)g,
      (__attribute__((address_space(3))) uint32_t*)(uint32_t)(uintptr_t)l,
      16, 0, 0);
}

__device__ __forceinline__ bfx8 ldfrag(const void* p) {
  sx8 r = *(const sx8*)p;
  return __builtin_bit_cast(bfx8, r);
}

#define MFMA(A, B, C) __builtin_amdgcn_mfma_f32_16x16x32_bf16((A), (B), (C), 0, 0, 0)

// ---------- kernel 1: f32 -> bf16 convert + row norms (f32) ----------

__global__ __launch_bounds__(256) void cmc_convert(
    const float* __restrict__ in, unsigned short* __restrict__ xb,
    float* __restrict__ lnorm) {
  const int row = blockIdx.x;           // 0 .. 3*4096-1
  const int tid = threadIdx.x;
  const fx4 v = *(const fx4*)(in + (size_t)row * ND + tid * 4);
  ux4 o;
  o[0] = f2bf(v[0]); o[1] = f2bf(v[1]); o[2] = f2bf(v[2]); o[3] = f2bf(v[3]);
  *(ux4*)(xb + (size_t)row * ND + tid * 4) = o;
  float ss = v[0]*v[0] + v[1]*v[1] + v[2]*v[2] + v[3]*v[3];
  #pragma unroll
  for (int d = 1; d < 64; d <<= 1) ss += __shfl_xor(ss, d);
  __shared__ float sred[4];
  if ((tid & 63) == 0) sred[tid >> 6] = ss;
  __syncthreads();
  if (tid == 0) lnorm[row] = sqrtf(sred[0] + sred[1] + sred[2] + sred[3]);
}

// ---------- 256x256 gram, BK=64, 8 waves, 4 fine phases per K-tile ----------
// LDS per buffer (2 buffers x 64 KiB): A[256][64] bf16 @+0, B[256][64] @+32768,
// row stride 128 B, XOR-swizzled: elem (r,c) at byte r*128 + ((c*2) ^ ((r&7)<<4)).
// global_load_lds writes linearly; source addr pre-swizzled per-lane (rule #21).
//
// Phase q of tile t: {stage 1 half of tile t+1 | vmcnt gate | BAR1 |
//   ds_reads (B@q0, A-frags for q+1) | lgkmcnt(4) | 16 MFMA (m{2q,2q+1}) | BAR2}
// Gload ledger (per thread, 2 gloads/half): vmcnt(2)@q0 forces current tile's
// B halves landed; vmcnt(4)@q3 forces next tile's A halves (read cross-buffer
// at q3). Stage into tile t's own buffer first occurs at t+1.q0, after t.q3's
// BAR2, by which point all reads of that buffer have completed.

template<int Q, bool FIRST, bool LAST>
__device__ __forceinline__ void phase_q(
    char* smem, int t, int w,
    const unsigned short* const (&pA)[4], const unsigned short* const (&pB)[4],
    int rdA0, int rdB0, bfx8 (&aR)[2][4], bfx8 (&b)[8], fx4 (&acc)[8][4]) {
  char* bufA = smem + (t & 1) * 65536;
  char* bufB = bufA + 32768;
  char* nb   = smem + ((t + 1) & 1) * 65536;   // staging dest (tile t+1)

  // ---- stage one half-tile of tile t+1 ----
  if (!LAST) {
    const int k1 = (t + 1) * 64;
    if (Q == 0) { gload16(pA[0] + k1, nb + 0*8192 + w*1024);
                  gload16(pA[1] + k1, nb + 1*8192 + w*1024); }
    if (Q == 1) { gload16(pA[2] + k1, nb + 2*8192 + w*1024);
                  gload16(pA[3] + k1, nb + 3*8192 + w*1024); }
    if (Q == 2) { gload16(pB[0] + k1, nb + 32768 + 0*8192 + w*1024);
                  gload16(pB[1] + k1, nb + 32768 + 1*8192 + w*1024); }
    if (Q == 3) { gload16(pB[2] + k1, nb + 32768 + 2*8192 + w*1024);
                  gload16(pB[3] + k1, nb + 32768 + 3*8192 + w*1024); }
  }
  // ---- vmcnt gate (counted; never drains mid-stream) ----
  if (Q == 0) {
    if (LAST) asm volatile("s_waitcnt vmcnt(0)" ::: "memory");
    else      asm volatile("s_waitcnt vmcnt(2)" ::: "memory");
  }
  if (Q == 3 && !LAST) asm volatile("s_waitcnt vmcnt(4)" ::: "memory");
  __builtin_amdgcn_s_barrier();               // BAR1: all waves' halves landed
  __builtin_amdgcn_sched_barrier(0);

  // ---- ds_reads ----
  if (Q == 0) {
    if (FIRST) {
      #pragma unroll
      for (int mm = 0; mm < 2; ++mm) {        // a_cur m{0,1} (normally from prev q3)
        const int ro = rdA0 + mm * 2048;
        aR[0][mm*2]   = ldfrag(bufA + ro);
        aR[0][mm*2+1] = ldfrag(bufA + (ro ^ 64));
      }
    }
    #pragma unroll
    for (int n = 0; n < 4; ++n) {             // B: all n, both kh
      const int ro = rdB0 + n * 2048;
      b[n*2]   = ldfrag(bufB + ro);
      b[n*2+1] = ldfrag(bufB + (ro ^ 64));
    }
  }
  if (Q < 3) {                                // prefetch A for phase Q+1
    #pragma unroll
    for (int mm = 0; mm < 2; ++mm) {
      const int ro = rdA0 + (2*Q + 2 + mm) * 2048;
      aR[(Q+1)&1][mm*2]   = ldfrag(bufA + ro);
      aR[(Q+1)&1][mm*2+1] = ldfrag(bufA + (ro ^ 64));
    }
  } else if (!LAST) {                         // prefetch next tile's A m{0,1}
    #pragma unroll
    for (int mm = 0; mm < 2; ++mm) {
      const int ro = rdA0 + mm * 2048;
      aR[0][mm*2]   = ldfrag(nb + ro);
      aR[0][mm*2+1] = ldfrag(nb + (ro ^ 64));
    }
  }
  // ---- operand wait (leave only the just-issued prefetch outstanding) ----
  if (Q == 3 && LAST) asm volatile("s_waitcnt lgkmcnt(0)" ::: "memory");
  else                asm volatile("s_waitcnt lgkmcnt(4)" ::: "memory");
  __builtin_amdgcn_sched_barrier(0);          // rule 18: pin MFMA below the wait

  // ---- 16 MFMA: m{2Q, 2Q+1} x n0-3 x kh0-1 ----
  __builtin_amdgcn_s_setprio(1);
  #pragma unroll
  for (int mm = 0; mm < 2; ++mm)
    #pragma unroll
    for (int n = 0; n < 4; ++n) {
      acc[2*Q+mm][n] = MFMA(aR[Q&1][mm*2],   b[n*2],   acc[2*Q+mm][n]);
      acc[2*Q+mm][n] = MFMA(aR[Q&1][mm*2+1], b[n*2+1], acc[2*Q+mm][n]);
    }
  __builtin_amdgcn_s_setprio(0);
  __builtin_amdgcn_sched_barrier(0);
  __builtin_amdgcn_s_barrier();               // BAR2
}

template<bool FIRST, bool LAST>
__device__ __forceinline__ void tile4(
    char* smem, int t, int w,
    const unsigned short* const (&pA)[4], const unsigned short* const (&pB)[4],
    int rdA0, int rdB0, bfx8 (&aR)[2][4], bfx8 (&b)[8], fx4 (&acc)[8][4]) {
  phase_q<0, FIRST, LAST>(smem, t, w, pA, pB, rdA0, rdB0, aR, b, acc);
  phase_q<1, FIRST, LAST>(smem, t, w, pA, pB, rdA0, rdB0, aR, b, acc);
  phase_q<2, FIRST, LAST>(smem, t, w, pA, pB, rdA0, rdB0, aR, b, acc);
  phase_q<3, FIRST, LAST>(smem, t, w, pA, pB, rdA0, rdB0, aR, b, acc);
}

__device__ __forceinline__ void gram256(
    const unsigned short* __restrict__ Xi, const unsigned short* __restrict__ Xj,
    int rb, int cb, char* smem, int tid, fx4 (&acc)[8][4]) {
  const int l = tid & 63, w = tid >> 6;
  const int wm = w >> 2, wn = w & 3;
  const int lrow = l >> 3, slot = l & 7;
  // pre-swizzled global source (element offset within row)
  const int srcoff = ((slot * 16) ^ (lrow << 4)) >> 1;
  const unsigned short* pA[4];
  const unsigned short* pB[4];
  #pragma unroll
  for (int s = 0; s < 4; ++s) {
    pA[s] = Xi + (size_t)(rb + s * 64 + w * 8 + lrow) * ND + srcoff;
    pB[s] = Xj + (size_t)(cb + s * 64 + w * 8 + lrow) * ND + srcoff;
  }
  // swizzled read offsets
  const int c0 = ((l >> 4) * 16) ^ ((l & 7) << 4);
  const int rdA0 = (wm * 128 + (l & 15)) * 128 + c0;
  const int rdB0 = (wn * 64 + (l & 15)) * 128 + c0;
  #pragma unroll
  for (int m = 0; m < 8; ++m)
    #pragma unroll
    for (int n = 0; n < 4; ++n) acc[m][n] = fx4{0.f, 0.f, 0.f, 0.f};

  // prologue: stage tile 0 entirely (8 gloads)
  {
    char* dA = smem;
    char* dB = smem + 32768;
    #pragma unroll
    for (int s = 0; s < 4; ++s) {
      gload16(pA[s], dA + s * 8192 + w * 1024);
      gload16(pB[s], dB + s * 8192 + w * 1024);
    }
  }
  bfx8 aR[2][4];
  bfx8 b[8];
  tile4<true, false>(smem, 0, w, pA, pB, rdA0, rdB0, aR, b, acc);
  for (int t = 1; t < NT - 1; ++t)
    tile4<false, false>(smem, t, w, pA, pB, rdA0, rdB0, aR, b, acc);
  tile4<false, true>(smem, NT - 1, w, pA, pB, rdA0, rdB0, aR, b, acc);
  __builtin_amdgcn_sched_barrier(0);
}

// ---------- kernel 2: per-modal self-gram -> bitmask (upper-tri + transpose) ----------

__global__ __launch_bounds__(512, 2) void cmc_selfmask(
    const unsigned short* __restrict__ xb, const float* __restrict__ lnorm,
    uint32_t* __restrict__ maskw) {
  __shared__ __align__(16) char smem[131072];
  const int md = blockIdx.z;
  const int bx = blockIdx.x, by = blockIdx.y;
  if (by > bx) return;                   // symmetric: upper triangle only
  const int rb = by * 256, cb = bx * 256;
  const int tid = threadIdx.x;
  const int l = tid & 63, w = tid >> 6;
  const int wr = w >> 2, wc = w & 3;
  const int g = l >> 4;

  const unsigned short* X = xb + (size_t)md * NB * ND;
  fx4 acc[8][4];
  gram256(X, X, rb, cb, smem, tid, acc);

  // epilogue: threshold -> 256x256 bit tile in LDS (reuse smem)
  uint32_t* tile = (uint32_t*)smem;      // [256][8] words = 8 KiB
  float* Lr = (float*)(smem + 8192);
  float* Lc = (float*)(smem + 9216);
  if (tid < 256) {
    Lr[tid] = lnorm[md * NB + rb + tid];
    Lc[tid] = lnorm[md * NB + cb + tid];
  }
  __syncthreads();

  #pragma unroll
  for (int m = 0; m < 8; ++m)
    #pragma unroll
    for (int r4 = 0; r4 < 4; ++r4) {
      const int rl = wr * 128 + m * 16 + g * 4 + r4;
      uint64_t bb[4];
      #pragma unroll
      for (int n = 0; n < 4; ++n) {
        const int cl = wc * 64 + n * 16 + (l & 15);
        const float cv = acc[m][n][r4] / fmaxf(Lr[rl] * Lc[cl], CEPS);
        bb[n] = __ballot(cv <= CTHR);
      }
      if ((l & 15) == 0) {
        const uint32_t w0 = (uint32_t)((bb[0] >> (16 * g)) & 0xFFFF) |
                            ((uint32_t)((bb[1] >> (16 * g)) & 0xFFFF) << 16);
        const uint32_t w1 = (uint32_t)((bb[2] >> (16 * g)) & 0xFFFF) |
                            ((uint32_t)((bb[3] >> (16 * g)) & 0xFFFF) << 16);
        tile[rl * 8 + wc * 2]     = w0;
        tile[rl * 8 + wc * 2 + 1] = w1;
      }
    }
  __syncthreads();

  // direct region: rows [rb,+256) x words [cb/32,+8) — exclusively owned
  for (int t = tid; t < 2048; t += 512) {
    const int row = t >> 3, wd = t & 7;
    maskw[((size_t)md * NB + rb + row) * 128 + (cb >> 5) + wd] = tile[t];
  }
  // transposed region: rows [cb,+256) x words [rb/32,+8)
  if (by != bx) {
    for (int t = tid; t < 2048; t += 512) {
      const int crow = t & 255;
      const int wp = t >> 8;
      uint32_t wv = 0;
      #pragma unroll
      for (int r = 0; r < 32; ++r) {
        const uint32_t bit = (tile[(wp * 32 + r) * 8 + (crow >> 5)] >> (crow & 31)) & 1u;
        wv |= bit << r;
      }
      maskw[((size_t)md * NB + cb + crow) * 128 + (rb >> 5) + wp] = wv;
    }
  }
}

// ---------- kernel 3: per-pair cross gram + masked exp row-partials ----------

__global__ __launch_bounds__(512, 2) void cmc_pair(
    const unsigned short* __restrict__ xb, const float* __restrict__ lnorm,
    const uint32_t* __restrict__ maskw,
    float* __restrict__ sumexp, float* __restrict__ cntrow,
    float* __restrict__ diagv) {
  __shared__ __align__(16) char smem[131072];
  const int p = blockIdx.z;              // pair: 0->(0,1) 1->(0,2) 2->(1,2)
  const int mi = (p == 2) ? 1 : 0;
  const int mj = (p == 0) ? 1 : 2;
  const int rb = blockIdx.y * 256;
  const int cb = blockIdx.x * 256;
  const int tid = threadIdx.x;
  const int l = tid & 63, w = tid >> 6;
  const int wr = w >> 2, wc = w & 3;
  const int g = l >> 4;

  const unsigned short* Xi = xb + (size_t)mi * NB * ND;
  const unsigned short* Xj = xb + (size_t)mj * NB * ND;

  fx4 acc[8][4];
  gram256(Xi, Xj, rb, cb, smem, tid, acc);

  // epilogue: stage masks + norms into LDS (reuse smem)
  uint32_t* Mt = (uint32_t*)smem;        // Mi [256][8] then Mj [256][8]
  float* Lri = (float*)(smem + 16384);
  float* Lcj = (float*)(smem + 17408);
  for (int t = tid; t < 2048; t += 512) {
    const int row = t >> 3, wd = t & 7;
    Mt[t]        = maskw[((size_t)mi * NB + rb + row) * 128 + (cb >> 5) + wd];
    Mt[2048 + t] = maskw[((size_t)mj * NB + rb + row) * 128 + (cb >> 5) + wd];
  }
  if (tid < 256) {
    Lri[tid] = lnorm[mi * NB + rb + tid];
    Lcj[tid] = lnorm[mj * NB + cb + tid];
  }
  __syncthreads();

  #pragma unroll
  for (int m = 0; m < 8; ++m)
    #pragma unroll
    for (int r4 = 0; r4 < 4; ++r4) {
      const int rl = wr * 128 + m * 16 + g * 4 + r4;
      const int rg = rb + rl;
      float se = 0.f, ct = 0.f;
      #pragma unroll
      for (int n = 0; n < 4; ++n) {
        const int cl = wc * 64 + n * 16 + (l & 15);
        const int cg = cb + cl;
        const uint32_t bi = (Mt[rl * 8 + (cl >> 5)] >> (cl & 31)) & 1u;
        const uint32_t bj = (Mt[2048 + rl * 8 + (cl >> 5)] >> (cl & 31)) & 1u;
        const bool msk = bi | bj | (rg == cg);
        const float logit = acc[m][n][r4] / fmaxf(Lri[rl] * Lcj[cl], CEPS) / 0.1f;
        if (rg == cg) diagv[p * NB + rg] = logit;
        if (msk) { se += __expf(logit); ct += 1.f; }
      }
      #pragma unroll
      for (int d0 = 1; d0 < 16; d0 <<= 1) {
        se += __shfl_xor(se, d0);
        ct += __shfl_xor(ct, d0);
      }
      if ((l & 15) == 0) {
        atomicAdd(&sumexp[p * NB + rg], se);
        atomicAdd(&cntrow[p * NB + rg], ct);
      }
    }
}

// ---------- kernel 4: finalize ----------

__global__ __launch_bounds__(256) void cmc_final(
    const float* __restrict__ sumexp, const float* __restrict__ cntrow,
    const float* __restrict__ diagv, float* __restrict__ out) {
  const int tid = threadIdx.x;
  __shared__ float sred[8];
  float lsum = 0.f;
  for (int p = 0; p < 3; ++p) {
    float t = 0.f, c = 0.f;
    for (int r = tid; r < NB; r += 256) {
      const float cnt = cntrow[p * NB + r];
      if (cnt > 1.0f) {
        t += logf(sumexp[p * NB + r]) - diagv[p * NB + r];
        c += 1.f;
      }
    }
    #pragma unroll
    for (int d = 1; d < 64; d <<= 1) { t += __shfl_xor(t, d); c += __shfl_xor(c, d); }
    if ((tid & 63) == 0) { sred[(tid >> 6) * 2] = t; sred[(tid >> 6) * 2 + 1] = c; }
    __syncthreads();
    if (tid == 0) {
      const float tt = sred[0] + sred[2] + sred[4] + sred[6];
      const float cc = sred[1] + sred[3] + sred[5] + sred[7];
      lsum += (cc > 0.f) ? tt / fmaxf(cc, 1.f) : 0.f;
    }
    __syncthreads();
  }
  if (tid == 0) out[0] = lsum / 3.0f;
}

// ---------- launch ----------

extern "C" void kernel_launch(void* const* d_in, const int* in_sizes, int n_in,
                              void* d_out, int out_size, void* d_ws, size_t ws_size,
                              hipStream_t stream) {
  const float* in = (const float*)d_in[0];
  float* out = (float*)d_out;
  char* ws = (char*)d_ws;

  const size_t XB_BYTES = (size_t)3 * NB * ND * sizeof(unsigned short); // 25,165,824
  unsigned short* xb = (unsigned short*)ws;
  float* lnorm  = (float*)(ws + XB_BYTES);
  float* sumexp = lnorm + 3 * NB;
  float* cntrow = sumexp + 3 * NB;
  float* diagv  = cntrow + 3 * NB;
  uint32_t* maskw = (uint32_t*)(diagv + 3 * NB);   // [3][4096][128] words = 6 MB

  // zero the atomically-accumulated per-row buffers (sumexp + cntrow contiguous)
  hipMemsetAsync(sumexp, 0, (size_t)2 * 3 * NB * sizeof(float), stream);

  cmc_convert<<<3 * NB, 256, 0, stream>>>(in, xb, lnorm);
  cmc_selfmask<<<dim3(NB / 256, NB / 256, 3), 512, 0, stream>>>(xb, lnorm, maskw);
  cmc_pair<<<dim3(NB / 256, NB / 256, 3), 512, 0, stream>>>(xb, lnorm, maskw, sumexp, cntrow, diagv);
  cmc_final<<<1, 256, 0, stream>>>(sumexp, cntrow, diagv, out);
}